// Round 4
// baseline (672.782 us; speedup 1.0000x reference)
//
#include <hip/hip_runtime.h>
#include <hip/hip_fp16.h>
#include <math.h>

typedef _Float16 f16;
typedef unsigned int u32;
typedef _Float16 f16x8 __attribute__((ext_vector_type(8)));
typedef _Float16 f16x4 __attribute__((ext_vector_type(4)));
typedef float    f32x4 __attribute__((ext_vector_type(4)));

constexpr int LEN  = 512;
constexpr int HID  = 512;
constexpr int BATCH = 64;

// ---- async global->LDS, 16B per lane. lds ptr must be wave-uniform. ----
__device__ __forceinline__ void gload16(const f16* g, f16* l) {
    __builtin_amdgcn_global_load_lds((const __attribute__((address_space(1))) u32*)g,
                                     (__attribute__((address_space(3))) u32*)l,
                                     16, 0, 0);
}

__device__ __forceinline__ float silu_f(float v) {
    return v * __builtin_amdgcn_rcpf(1.f + __expf(-v));
}

// ============================================================================
// 256x128 8-wave core, BK=32, 3 stage bufs (72KB).
// Pipeline: 2-ahead counted vmcnt (see R3 notes). Chunk-XOR swizzle both
// sides: source chunk = (tid&3)^((row>>1)&3); read slot = (lane>>4)^((mf>>1)&3).
// 16B-position = (row&1)<<2 | slot -> 16-row frag group covers all 8 positions
// twice = 2-way = free (m136).
// ============================================================================
#define TUNIT 12288   // f16 per K-tile buffer: A 256x32 (8192) + B 128x32 (4096)
#define EPIP  136     // epilogue pitch (272B/row, 16B-aligned)
#define SBUF  36864   // f16 offset of S region in k_attn (after 3 stage bufs)

__device__ __forceinline__ void stage_pass(const f16* __restrict__ g, f16* l) {
    const int tid = threadIdx.x;
    const int row = tid >> 2;                       // 0..127
    const int sc  = (tid & 3) ^ ((row >> 1) & 3);   // inverse-swizzled chunk
    gload16(g + (size_t)row * 512 + sc * 8, l + (tid >> 6) * 512);
}

__device__ __forceinline__ void stage_tile(const f16* __restrict__ A,
                                           const f16* __restrict__ B,
                                           int kt, f16* buf) {
    stage_pass(A + kt * 32,             buf);            // A rows   0..127
    stage_pass(A + kt * 32 + 128 * 512, buf + 4096);     // A rows 128..255
    stage_pass(B + kt * 32,             buf + 8192);     // B rows   0..127
}

// acc[4][4]: wave (wr,wc): rows wr*64..+63, cols wc*64..+63 of the 256x128 tile
__device__ __forceinline__ void gemm8b(const f16* __restrict__ A,
                                       const f16* __restrict__ B,
                                       int ksteps, f16* lds, f32x4 acc[4][4])
{
    const int lane = threadIdx.x & 63;
    const int wv   = threadIdx.x >> 6;
    const int wr = wv >> 1, wc = wv & 1;
    const int mf = lane & 15;
    const int slot = ((lane >> 4) ^ ((mf >> 1) & 3)) * 8;   // (row>>1)&3 == (mf>>1)&3
    const int aoff = (wr * 64 + mf) * 32 + slot;
    const int boff = (wc * 64 + mf) * 32 + slot + 8192;

    #pragma unroll
    for (int m = 0; m < 4; ++m)
        #pragma unroll
        for (int n = 0; n < 4; ++n)
            acc[m][n] = (f32x4){0.f, 0.f, 0.f, 0.f};

    stage_tile(A, B, 0, lds);
    stage_tile(A, B, 1, lds + TUNIT);
    asm volatile("s_waitcnt vmcnt(3)" ::: "memory");   // tile0 retired, tile1 in flight
    __builtin_amdgcn_s_barrier();

    int cb = 0;
    for (int kt = 0; kt < ksteps; ++kt) {
        f16* buf = lds + cb * TUNIT;
        f16x8 af[4], bf[4];
        #pragma unroll
        for (int m = 0; m < 4; ++m) af[m] = *(const f16x8*)(buf + aoff + m * 512);
        #pragma unroll
        for (int n = 0; n < 4; ++n) bf[n] = *(const f16x8*)(buf + boff + n * 512);
        if (kt + 2 < ksteps) {
            int nb = cb + 2; if (nb >= 3) nb -= 3;
            stage_tile(A, B, kt + 2, lds + nb * TUNIT);
        }
        asm volatile("s_waitcnt lgkmcnt(0)" ::: "memory");
        __builtin_amdgcn_sched_barrier(0);
        __builtin_amdgcn_s_setprio(1);
        #pragma unroll
        for (int m = 0; m < 4; ++m)
            #pragma unroll
            for (int n = 0; n < 4; ++n)
                acc[m][n] = __builtin_amdgcn_mfma_f32_16x16x32_f16(af[m], bf[n], acc[m][n], 0, 0, 0);
        __builtin_amdgcn_s_setprio(0);
        if (kt + 3 <= ksteps) {                  // kt <= ksteps-3: tile kt+1 ready
            asm volatile("s_waitcnt vmcnt(3)" ::: "memory");
            __builtin_amdgcn_s_barrier();
        } else if (kt + 2 == ksteps) {           // last prefetched tile
            asm volatile("s_waitcnt vmcnt(0)" ::: "memory");
            __builtin_amdgcn_s_barrier();
        }
        cb = cb + 1; if (cb >= 3) cb = 0;
    }
}

// C/D layout (16x16x32): col = lane&15, row = (lane>>4)*4 + reg   [m89-verified]
#define EPI_IDX() \
    const int lane = threadIdx.x & 63, wv_ = threadIdx.x >> 6;  \
    const int wr = wv_ >> 1, wc = wv_ & 1;                      \
    const int c0 = lane & 15, r0 = (lane >> 4) * 4;

// coalesced copy of half-tile h (rows h*128..+127) from lds[128][EPIP]
__device__ __forceinline__ void copy_half(const f16* lds, f16* __restrict__ gout,
                                          int ldo, int h) {
    const int tid = threadIdx.x;
    #pragma unroll
    for (int ph = 0; ph < 4; ++ph) {
        const int r = ph * 32 + (tid >> 4);
        const int c = (tid & 15) * 8;
        *(f16x8*)(gout + (size_t)(h * 128 + r) * ldo + c) = *(const f16x8*)(lds + r * EPIP + c);
    }
}

// ---- fused z | v^T. 1024 blocks: slab s's 8 consumers share bid%8 (XCD) ----
// bid = (s&7) + 8*ci + 64*(s>>3); ci 0-3: z nt=ci; ci 4-7: vt (ht,lh)
__global__ __launch_bounds__(512, 4) void k_zv8(const f16* __restrict__ x,
                                                const f16* __restrict__ Wzh,
                                                const f16* __restrict__ Wvh,
                                                f16* __restrict__ z,
                                                f16* __restrict__ vt)
{
    __shared__ __align__(16) f16 lds[3 * TUNIT];   // 72KB
    const int bid = blockIdx.x;
    const int s  = (bid & 7) + 8 * (bid >> 6);     // x-slab 0..127 (256 rows)
    const int ci = (bid >> 3) & 7;
    const f16* A; const f16* Bm; f16* gout;
    if (ci < 4) {                                  // z[s rows, nt=ci cols]
        A = x + (size_t)s * 256 * HID;
        Bm = Wzh + (size_t)ci * 128 * HID;
        gout = z + (size_t)s * 256 * HID + ci * 128;
    } else {                                       // vt[h rows, l cols] = Wv @ x^T
        const int ht = (ci - 4) >> 1, lh = (ci - 4) & 1;
        A = Wvh + (size_t)ht * 256 * HID;
        Bm = x + ((size_t)s * 256 + lh * 128) * HID;
        gout = vt + (size_t)(s >> 1) * LEN * HID + (size_t)ht * 256 * LEN
                  + (s & 1) * 256 + lh * 128;
    }
    f32x4 acc[4][4];
    gemm8b(A, Bm, HID / 32, lds, acc);
    __syncthreads();
    EPI_IDX();
    #pragma unroll
    for (int h = 0; h < 2; ++h) {
        if ((wr >> 1) == h) {
            const int rb = (wr & 1) * 64;
            #pragma unroll
            for (int m = 0; m < 4; ++m)
                #pragma unroll
                for (int n = 0; n < 4; ++n)
                    #pragma unroll
                    for (int i = 0; i < 4; ++i)
                        lds[(rb + m * 16 + r0 + i) * EPIP + wc * 64 + n * 16 + c0] =
                            (f16)silu_f(acc[m][n][i]);
        }
        __syncthreads();
        copy_half(lds, gout, 512, h);
        __syncthreads();
    }
}

// ---- fused q | k projections, same structure over z-slabs ----
__global__ __launch_bounds__(512, 4) void k_qkp8(const f16* __restrict__ z,
                                                 const f16* __restrict__ Wqh,
                                                 const f16* __restrict__ Wkh,
                                                 const float* __restrict__ gq,
                                                 const float* __restrict__ bq,
                                                 const float* __restrict__ gk,
                                                 const float* __restrict__ bk,
                                                 f16* __restrict__ qh,
                                                 f16* __restrict__ kh)
{
    __shared__ __align__(16) f16 lds[3 * TUNIT];
    const int bid = blockIdx.x;
    const int s  = (bid & 7) + 8 * (bid >> 6);
    const int ci = (bid >> 3) & 7;
    const bool isq = ci < 4;
    const int nt = ci & 3;
    const f16* W = isq ? Wqh : Wkh;
    const float* g  = isq ? gq : gk;
    const float* be = isq ? bq : bk;
    f16* outp = isq ? qh : kh;
    f32x4 acc[4][4];
    gemm8b(z + (size_t)s * 256 * HID, W + (size_t)nt * 128 * HID, HID / 32, lds, acc);
    __syncthreads();
    EPI_IDX();
    f16* gbase = outp + (size_t)s * 256 * HID + nt * 128;
    #pragma unroll
    for (int h = 0; h < 2; ++h) {
        if ((wr >> 1) == h) {
            const int rb = (wr & 1) * 64;
            #pragma unroll
            for (int n = 0; n < 4; ++n) {
                const int col = wc * 64 + n * 16 + c0;
                const int jg = nt * 128 + col;
                const float ga = g[jg], ba = be[jg];
                #pragma unroll
                for (int m = 0; m < 4; ++m)
                    #pragma unroll
                    for (int i = 0; i < 4; ++i)
                        lds[(rb + m * 16 + r0 + i) * EPIP + col] =
                            (f16)((acc[m][n][i] * ga + ba) * 1024.f);
            }
        }
        __syncthreads();
        copy_half(lds, gbase, 512, h);
        __syncthreads();
    }
}

// ============================================================================
// fused attention: S = relu(mask(q@k^T)*smask)^2 (f16, LDS-only) ; out += S@vt^T
// Eliminates the p round-trip (96MB HBM) and one launch boundary.
// Block = (b, lt row-panel 256, hh out-col eighth 128). kv len = (lt+1)*256.
// Per mt (128 kv cols): S-phase = gemm8b (16 iters) -> epilogue writes S-tile
// f16 into a stage-buf-layout LDS region (same chunk-XOR swizzle, so PV A-frag
// reads reuse aoff/slot) -> PV 4 iters with V frags read DIRECT FROM GLOBAL
// (L2-resident vt, 16-rows x 64B line-coalesced). LDS = 72KB stage + 64KB S.
// Numerics identical to the split kernels: 2^10 q,k lifts, (f16)(v*v), 2^-58.
// ============================================================================
__global__ __launch_bounds__(512, 2) void k_attn(const f16* __restrict__ q,
                                                 const f16* __restrict__ kmat,
                                                 const f16* __restrict__ vt,
                                                 const int* __restrict__ mask,
                                                 const float* __restrict__ smask,
                                                 float* __restrict__ out)
{
    __shared__ __align__(16) f16 lds[SBUF + 32768];   // 136KB
    const int bid = blockIdx.x;
    const int inner = (bid >> 3) & 7;
    const int b = (bid & 7) + 8 * (bid >> 6);
    const int lt = 1 - (inner >> 2), hh = inner & 3;   // long row-panels first
    const int nmt = (lt + 1) * 2;

    const int lane = threadIdx.x & 63;
    const int wv   = threadIdx.x >> 6;
    const int wr = wv >> 1, wc = wv & 1;
    const int c0 = lane & 15, r0 = (lane >> 4) * 4;
    const int mf = lane & 15;
    const int kfr = (lane >> 4) * 8;
    const int slot = ((lane >> 4) ^ ((mf >> 1) & 3)) * 8;

    const size_t boff = (size_t)b * LEN * HID;
    const f16* qpan = q + boff + (size_t)lt * 256 * HID;
    // per-lane V row pointer: global h = hh*128 + wc*64 + n*16 + mf
    const f16* vrow = vt + (size_t)b * HID * LEN + (size_t)(hh * 128 + wc * 64 + mf) * LEN;

    f32x4 acc_o[4][4];
    #pragma unroll
    for (int m = 0; m < 4; ++m)
        #pragma unroll
        for (int n = 0; n < 4; ++n)
            acc_o[m][n] = (f32x4){0.f, 0.f, 0.f, 0.f};

    for (int mt = 0; mt < nmt; ++mt) {
        // ---- S-phase: 256x128 score tile over K=512 ----
        f32x4 acc_s[4][4];
        gemm8b(qpan, kmat + boff + (size_t)mt * 128 * HID, HID / 32, lds, acc_s);

        // ---- epilogue: mask + smask + relu^2 -> f16 S-tile in LDS ----
        #pragma unroll
        for (int n = 0; n < 4; ++n) {
            const int c_l = wc * 64 + n * 16 + c0;          // 0..127
            const int m_g = mt * 128 + c_l;                 // kv index
            const int keepcol = mask[b * LEN + m_g];
            const int sb = c_l >> 5;                        // 32-col sub-buf
            const int col5 = c_l & 31;
            #pragma unroll
            for (int m = 0; m < 4; ++m)
                #pragma unroll
                for (int i = 0; i < 4; ++i) {
                    const int r_l = wr * 64 + m * 16 + r0 + i;   // 0..255
                    const int l_g = lt * 256 + r_l;              // query index
                    const bool keep = (l_g == m_g) || ((m_g <= l_g) && (keepcol != 0));
                    float v = keep ? acc_s[m][n][i] * smask[l_g * LEN + m_g] : 0.f;
                    v = fmaxf(v, 0.f);
                    const int sch = (col5 >> 3) ^ ((r_l >> 1) & 3);
                    lds[SBUF + sb * 8192 + r_l * 32 + sch * 8 + (col5 & 7)] = (f16)(v * v);
                }
        }
        __syncthreads();

        // ---- PV: acc_o += S(256x128) @ vt-chunk^T, V direct from global ----
        #pragma unroll
        for (int ks = 0; ks < 4; ++ks) {
            f16x8 af[4], bf[4];
            #pragma unroll
            for (int m = 0; m < 4; ++m)
                af[m] = *(const f16x8*)(lds + SBUF + ks * 8192 + (wr * 64 + mf) * 32 + slot + m * 512);
            #pragma unroll
            for (int n = 0; n < 4; ++n)
                bf[n] = *(const f16x8*)(vrow + (size_t)n * 16 * LEN + mt * 128 + ks * 32 + kfr);
            #pragma unroll
            for (int m = 0; m < 4; ++m)
                #pragma unroll
                for (int n = 0; n < 4; ++n)
                    acc_o[m][n] = __builtin_amdgcn_mfma_f32_16x16x32_f16(af[m], bf[n], acc_o[m][n], 0, 0, 0);
        }
        // next mt's first gemm8b barrier fences PV stragglers; S-LDS untouched
        // until the mt+1 epilogue, which is after barriers all waves pass.
    }

    // ---- out epilogue: undo 2^20 lift squared (2^40) and /(L*H): 2^-58 ----
    const float SCALE = 3.4694469519536142e-18f;
    #pragma unroll
    for (int m = 0; m < 4; ++m)
        #pragma unroll
        for (int n = 0; n < 4; ++n) {
            const int h_g = hh * 128 + wc * 64 + n * 16 + c0;
            #pragma unroll
            for (int i = 0; i < 4; ++i) {
                const int l_g = lt * 256 + wr * 64 + m * 16 + r0 + i;
                out[(size_t)b * LEN * HID + (size_t)l_g * HID + h_g] = acc_o[m][n][i] * SCALE;
            }
        }
}

// ---- one prep launch: gather(x) + 4x weight f2h + smask ----
__global__ __launch_bounds__(256) void k_prep(const int* __restrict__ pos,
                                              const float* __restrict__ item_emb,
                                              const float* __restrict__ pos_emb,
                                              f16* __restrict__ x,
                                              const float* __restrict__ Wz,
                                              const float* __restrict__ Wv,
                                              const float* __restrict__ Wq,
                                              const float* __restrict__ Wk,
                                              f16* __restrict__ Wzh,
                                              f16* __restrict__ Wvh,
                                              f16* __restrict__ Wqh,
                                              f16* __restrict__ Wkh,
                                              const float* __restrict__ sw,
                                              const float* __restrict__ gum,
                                              float* __restrict__ smask)
{
    const int bid = blockIdx.x;
    const int tid = threadIdx.x;
    if (bid < 16384) {                       // gather: x = item_emb[pos] + pos_emb
        const int t = bid * 256 + tid;
        const int i = t >> 7;
        const int c = t & 127;
        const int l = i & (LEN - 1);
        const int item = pos[i];
        const float4 a  = ((const float4*)(item_emb + (size_t)item * HID))[c];
        const float4 b4 = ((const float4*)(pos_emb + (size_t)l * HID))[c];
        f16x4 o = { (f16)(a.x + b4.x), (f16)(a.y + b4.y),
                    (f16)(a.z + b4.z), (f16)(a.w + b4.w) };
        *(f16x4*)(x + (size_t)t * 4) = o;
    } else if (bid < 16384 + 1024) {         // weight f32 -> f16
        const int r = bid - 16384;
        const int w = r >> 8;
        const float* s = (w == 0) ? Wz : (w == 1) ? Wv : (w == 2) ? Wq : Wk;
        f16* d = (w == 0) ? Wzh : (w == 1) ? Wvh : (w == 2) ? Wqh : Wkh;
        const int t = (r & 255) * 256 + tid;
        const float4 v = ((const float4*)s)[t];
        f16x4 o = { (f16)v.x, (f16)v.y, (f16)v.z, (f16)v.w };
        *(f16x4*)(d + (size_t)t * 4) = o;
    } else {                                 // gumbel-sigmoid smask (fp32)
        const int t = (bid - 16384 - 1024) * 256 + tid;
        const float4 w4 = ((const float4*)sw)[t];
        const float4 g4 = ((const float4*)gum)[t];
        float4 o;
        o.x = __builtin_amdgcn_rcpf(1.f + __expf(-(__logf(w4.x / (1.f - w4.x)) + g4.x) * 5.f));
        o.y = __builtin_amdgcn_rcpf(1.f + __expf(-(__logf(w4.y / (1.f - w4.y)) + g4.y) * 5.f));
        o.z = __builtin_amdgcn_rcpf(1.f + __expf(-(__logf(w4.z / (1.f - w4.z)) + g4.z) * 5.f));
        o.w = __builtin_amdgcn_rcpf(1.f + __expf(-(__logf(w4.w / (1.f - w4.w)) + g4.w) * 5.f));
        ((float4*)smask)[t] = o;
    }
}

extern "C" void kernel_launch(void* const* d_in, const int* in_sizes, int n_in,
                              void* d_out, int out_size, void* d_ws, size_t ws_size,
                              hipStream_t stream)
{
    const int*   positives = (const int*)  d_in[0];
    const int*   mask      = (const int*)  d_in[1];
    const float* item_emb  = (const float*)d_in[2];
    const float* pos_emb   = (const float*)d_in[3];
    const float* Wz        = (const float*)d_in[4];
    const float* Wv        = (const float*)d_in[5];
    const float* Wq        = (const float*)d_in[6];
    const float* Wk        = (const float*)d_in[7];
    const float* gamma_q   = (const float*)d_in[8];
    const float* beta_q    = (const float*)d_in[9];
    const float* gamma_k   = (const float*)d_in[10];
    const float* beta_k    = (const float*)d_in[11];
    const float* sparse_w  = (const float*)d_in[12];
    const float* gumbel    = (const float*)d_in[13];
    float* out = (float*)d_out;

    char* ws = (char*)d_ws;
    const size_t BUFB = (size_t)BATCH * LEN * HID * sizeof(f16);  // 32 MB
    f16* buf0 = (f16*)ws;                // x
    f16* buf1 = (f16*)(ws + BUFB);       // z
    f16* buf2 = (f16*)(ws + 2 * BUFB);   // vt
    f16* qh   = (f16*)(ws + 3 * BUFB);   // q (must outlive out-writes now)
    f16* kh   = (f16*)(ws + 4 * BUFB);   // k
    f16* Wzh  = (f16*)(ws + 5 * BUFB);
    f16* Wvh  = Wzh + LEN * HID;
    f16* Wqh  = Wvh + LEN * HID;
    f16* Wkh  = Wqh + LEN * HID;
    float* smask = (float*)(Wkh + LEN * HID);

    k_prep<<<16384 + 1024 + 256, 256, 0, stream>>>(
        positives, item_emb, pos_emb, buf0,
        Wz, Wv, Wq, Wk, Wzh, Wvh, Wqh, Wkh,
        sparse_w, gumbel, smask);

    k_zv8<<<1024, 512, 0, stream>>>(buf0, Wzh, Wvh, buf1, buf2);

    k_qkp8<<<1024, 512, 0, stream>>>(buf1, Wqh, Wkh,
                                     gamma_q, beta_q, gamma_k, beta_k, qh, kh);

    k_attn<<<512, 512, 0, stream>>>(qh, kh, buf2, mask, smask, out);
}

// Round 5
// 392.225 us; speedup vs baseline: 1.7153x; 1.7153x over previous
//
#include <hip/hip_runtime.h>
#include <hip/hip_fp16.h>
#include <math.h>

typedef _Float16 f16;
typedef unsigned int u32;
typedef _Float16 f16x8 __attribute__((ext_vector_type(8)));
typedef _Float16 f16x4 __attribute__((ext_vector_type(4)));
typedef float    f32x4 __attribute__((ext_vector_type(4)));

constexpr int LEN  = 512;
constexpr int HID  = 512;
constexpr int BATCH = 64;

// ---- async global->LDS, 16B per lane. lds ptr must be wave-uniform. ----
__device__ __forceinline__ void gload16(const f16* g, f16* l) {
    __builtin_amdgcn_global_load_lds((const __attribute__((address_space(1))) u32*)g,
                                     (__attribute__((address_space(3))) u32*)l,
                                     16, 0, 0);
}

__device__ __forceinline__ float silu_f(float v) {
    return v * __builtin_amdgcn_rcpf(1.f + __expf(-v));
}

// ============================================================================
// 256x256 8-wave m201-class phase core. BK=32, 4 tile-buffers (128KB LDS),
// tile-granular 3-ahead prefetch, counted vmcnt.
//
// Per K-tile: 2 phases, each the m201 sandwich:
//   {ds_read frags ; 2x gload stage of tile t+3} -> s_barrier -> lgkmcnt(0)
//   -> sched_barrier -> setprio(1) -> 16 MFMA -> setprio(0) -> [vmcnt] -> s_barrier
// Ledger (4 loads/thread per tile): prologue stages T0,T1,T2 (12), vmcnt(8)
// retires T0. Iter t stages T(t+3) (if <nt); end-of-tile wait:
//   t<nt-3: vmcnt(8) retires T(t+1); t==nt-3: vmcnt(4); t==nt-2: vmcnt(0).
// Race-freedom: buffer (t+3)&3 == (t-1)&3; tile t-1's last ds_reads complete
// before its pre-MFMA lgkmcnt(0), which precedes the post-MFMA barrier that
// the t-phase stage issues after -> strictly ordered, no overlap.
//
// LDS chunk swizzle (both sides, rule 21): pass = 128 rows x 32 k, row = 64B
// = 4 chunks of 16B; source chunk = (tid&3)^((row>>1)&3); read slot =
// ((lane>>4)^((mf>>1)&3)). 16B-position = (row&1)<<2|slot -> 16-row fragment
// group covers all 8 positions twice = 2-way = free (m136).
// ============================================================================
#define TP 16384   // f16 per tile buffer (32KB): A 2 passes + B 2 passes
#define EP 264     // epilogue pitch (528B/row, 16B-aligned, bank-rotating)

__device__ __forceinline__ void stage_pass(const f16* __restrict__ g, f16* l) {
    const int tid = threadIdx.x;
    const int row = tid >> 2;                       // 0..127
    const int sc  = (tid & 3) ^ ((row >> 1) & 3);   // inverse-swizzled chunk
    gload16(g + (size_t)row * 512 + sc * 8, l + (tid >> 6) * 512);
}

__device__ __forceinline__ void stage_tile(const f16* __restrict__ A,
                                           const f16* __restrict__ B,
                                           int t, f16* buf) {
    stage_pass(A + t * 32,             buf);            // A rows   0..127
    stage_pass(A + t * 32 + 128 * 512, buf + 4096);     // A rows 128..255
    stage_pass(B + t * 32,             buf + 8192);     // B rows   0..127
    stage_pass(B + t * 32 + 128 * 512, buf + 12288);    // B rows 128..255
}

// acc[8][4]: wave (wr=wv>>2, wc=wv&3) owns rows wr*128..+127, cols wc*64..+63
__device__ __forceinline__ void gemm8p(const f16* __restrict__ A,
                                       const f16* __restrict__ B,
                                       int nt, f16* lds, f32x4 acc[8][4])
{
    const int lane = threadIdx.x & 63;
    const int wv   = threadIdx.x >> 6;
    const int wr = wv >> 2, wc = wv & 3;
    const int mf = lane & 15;
    const int slot = ((lane >> 4) ^ ((mf >> 1) & 3)) * 8;
    const int abase = wr * 4096 + mf * 32 + slot;                      // A pass rh=wr
    const int bbase = 8192 + (wc >> 1) * 4096 + ((wc & 1) * 64 + mf) * 32 + slot;

    #pragma unroll
    for (int m = 0; m < 8; ++m)
        #pragma unroll
        for (int n = 0; n < 4; ++n)
            acc[m][n] = (f32x4){0.f, 0.f, 0.f, 0.f};

    stage_tile(A, B, 0, lds);
    stage_tile(A, B, 1, lds + TP);
    stage_tile(A, B, 2, lds + 2 * TP);
    asm volatile("s_waitcnt vmcnt(8)" ::: "memory");   // T0 retired; T1,T2 in flight
    __builtin_amdgcn_s_barrier();

    for (int t = 0; t < nt; ++t) {
        f16* buf  = lds + (t & 3) * TP;
        f16* nbuf = lds + ((t + 3) & 3) * TP;
        const bool st = (t + 3 < nt);
        f16x8 af[4], bf[4];

        // ---- phase A: rows 0..63 of wave tile ----
        #pragma unroll
        for (int m = 0; m < 4; ++m) af[m] = *(const f16x8*)(buf + abase + m * 512);
        #pragma unroll
        for (int n = 0; n < 4; ++n) bf[n] = *(const f16x8*)(buf + bbase + n * 512);
        if (st) {
            stage_pass(A + (t + 3) * 32,             nbuf);
            stage_pass(A + (t + 3) * 32 + 128 * 512, nbuf + 4096);
        }
        __builtin_amdgcn_s_barrier();
        asm volatile("s_waitcnt lgkmcnt(0)" ::: "memory");
        __builtin_amdgcn_sched_barrier(0);
        __builtin_amdgcn_s_setprio(1);
        #pragma unroll
        for (int m = 0; m < 4; ++m)
            #pragma unroll
            for (int n = 0; n < 4; ++n)
                acc[m][n] = __builtin_amdgcn_mfma_f32_16x16x32_f16(af[m], bf[n], acc[m][n], 0, 0, 0);
        __builtin_amdgcn_s_setprio(0);
        __builtin_amdgcn_s_barrier();

        // ---- phase B: rows 64..127 (bf held in regs) ----
        #pragma unroll
        for (int m = 0; m < 4; ++m) af[m] = *(const f16x8*)(buf + abase + (m + 4) * 512);
        if (st) {
            stage_pass(B + (t + 3) * 32,             nbuf + 8192);
            stage_pass(B + (t + 3) * 32 + 128 * 512, nbuf + 12288);
        }
        __builtin_amdgcn_s_barrier();
        asm volatile("s_waitcnt lgkmcnt(0)" ::: "memory");
        __builtin_amdgcn_sched_barrier(0);
        __builtin_amdgcn_s_setprio(1);
        #pragma unroll
        for (int m = 0; m < 4; ++m)
            #pragma unroll
            for (int n = 0; n < 4; ++n)
                acc[m + 4][n] = __builtin_amdgcn_mfma_f32_16x16x32_f16(af[m], bf[n], acc[m + 4][n], 0, 0, 0);
        __builtin_amdgcn_s_setprio(0);
        if (t < nt - 3)       { asm volatile("s_waitcnt vmcnt(8)" ::: "memory"); }
        else if (t == nt - 3) { asm volatile("s_waitcnt vmcnt(4)" ::: "memory"); }
        else if (t == nt - 2) { asm volatile("s_waitcnt vmcnt(0)" ::: "memory"); }
        __builtin_amdgcn_s_barrier();
    }
}

// C/D layout (16x16x32): col = lane&15, row = (lane>>4)*4 + reg   [m89-verified]
#define EPI_IDX() \
    const int lane = threadIdx.x & 63, wv_ = threadIdx.x >> 6;  \
    const int wr = wv_ >> 2, wc = wv_ & 3;                      \
    const int c0 = lane & 15, r0 = (lane >> 4) * 4;

// coalesced copy of rows h*128..+127 (256 cols) from lds[128][EP]
__device__ __forceinline__ void copy_half(const f16* lds, f16* __restrict__ gout,
                                          int ldo, int h) {
    const int tid = threadIdx.x;
    #pragma unroll
    for (int ph = 0; ph < 8; ++ph) {
        const int r = ph * 16 + (tid >> 5);
        const int c = (tid & 31) * 8;
        *(f16x8*)(gout + (size_t)(h * 128 + r) * ldo + c) = *(const f16x8*)(lds + r * EP + c);
    }
}

// ---- fused z | v^T, 256^2 tiles. 512 blocks, slab-grouped XCD swizzle ----
// bid = (s&7) + 8*ci + 32*(s>>3); ci 0,1: z col-tile ci; ci 2,3: vt ht=ci-2
__global__ __launch_bounds__(512, 2) void k_zv8(const f16* __restrict__ x,
                                                const f16* __restrict__ Wzh,
                                                const f16* __restrict__ Wvh,
                                                f16* __restrict__ z,
                                                f16* __restrict__ vt)
{
    __shared__ __align__(16) f16 lds[4 * TP];      // 128KB
    const int bid = blockIdx.x;
    const int s  = (bid & 7) + 8 * (bid >> 5);     // x-slab 0..127 (256 rows)
    const int ci = (bid >> 3) & 3;
    const f16* A; const f16* Bm; f16* gout;
    if (ci < 2) {                                  // z[s rows, ci col-tile]
        A = x + (size_t)s * 256 * HID;
        Bm = Wzh + (size_t)ci * 256 * HID;
        gout = z + (size_t)s * 256 * HID + ci * 256;
    } else {                                       // vt[h rows, l cols] = Wv @ x^T
        const int ht = ci - 2;
        A = Wvh + (size_t)ht * 256 * HID;
        Bm = x + (size_t)s * 256 * HID;
        gout = vt + (size_t)(s >> 1) * LEN * HID + (size_t)ht * 256 * LEN + (s & 1) * 256;
    }
    f32x4 acc[8][4];
    gemm8p(A, Bm, 16, lds, acc);
    EPI_IDX();
    __syncthreads();
    #pragma unroll
    for (int h = 0; h < 2; ++h) {
        if (wr == h) {
            #pragma unroll
            for (int m = 0; m < 8; ++m)
                #pragma unroll
                for (int n = 0; n < 4; ++n)
                    #pragma unroll
                    for (int i = 0; i < 4; ++i)
                        lds[(m * 16 + r0 + i) * EP + wc * 64 + n * 16 + c0] =
                            (f16)silu_f(acc[m][n][i]);
        }
        __syncthreads();
        copy_half(lds, gout, 512, h);
        __syncthreads();
    }
}

// ---- fused q | k projections over z-slabs ----
__global__ __launch_bounds__(512, 2) void k_qkp8(const f16* __restrict__ z,
                                                 const f16* __restrict__ Wqh,
                                                 const f16* __restrict__ Wkh,
                                                 const float* __restrict__ gq,
                                                 const float* __restrict__ bq,
                                                 const float* __restrict__ gk,
                                                 const float* __restrict__ bk,
                                                 f16* __restrict__ qh,
                                                 f16* __restrict__ kh)
{
    __shared__ __align__(16) f16 lds[4 * TP];
    const int bid = blockIdx.x;
    const int s  = (bid & 7) + 8 * (bid >> 5);
    const int ci = (bid >> 3) & 3;
    const bool isq = ci < 2;
    const int ct = ci & 1;
    const f16* W = isq ? Wqh : Wkh;
    const float* g  = isq ? gq : gk;
    const float* be = isq ? bq : bk;
    f16* outp = isq ? qh : kh;
    f32x4 acc[8][4];
    gemm8p(z + (size_t)s * 256 * HID, W + (size_t)ct * 256 * HID, 16, lds, acc);
    EPI_IDX();
    f16* gbase = outp + (size_t)s * 256 * HID + ct * 256;
    __syncthreads();
    #pragma unroll
    for (int h = 0; h < 2; ++h) {
        if (wr == h) {
            #pragma unroll
            for (int n = 0; n < 4; ++n) {
                const int col = wc * 64 + n * 16 + c0;
                const int jg = ct * 256 + col;
                const float ga = g[jg], ba = be[jg];
                #pragma unroll
                for (int m = 0; m < 8; ++m)
                    #pragma unroll
                    for (int i = 0; i < 4; ++i)
                        lds[(m * 16 + r0 + i) * EP + col] =
                            (f16)((acc[m][n][i] * ga + ba) * 1024.f);
            }
        }
        __syncthreads();
        copy_half(lds, gbase, 512, h);
        __syncthreads();
    }
}

// ---- batched q@k^T + mask + smask + relu^2 -> p. 3 tri-tiles of 256^2 ----
// 192 blocks: bid = (b&7) + 8*(t + 3*(b>>3))
__constant__ int LT3[3] = {0, 1, 1};
__constant__ int MT3[3] = {0, 0, 1};

__global__ __launch_bounds__(512, 2) void k_qk8(const f16* __restrict__ q,
                                                const f16* __restrict__ kmat,
                                                const int* __restrict__ mask,
                                                const float* __restrict__ smask,
                                                f16* __restrict__ p)
{
    __shared__ __align__(16) f16 lds[4 * TP];
    const int bid = blockIdx.x;
    const int tt = (bid >> 3) % 3;
    const int b = (bid & 7) + 8 * (bid / 24);
    const int lt = LT3[tt], mt = MT3[tt];
    const size_t boff = (size_t)b * LEN * HID;
    f32x4 acc[8][4];
    gemm8p(q + boff + (size_t)lt * 256 * HID,
           kmat + boff + (size_t)mt * 256 * HID, 16, lds, acc);
    EPI_IDX();
    f16* gbase = p + (size_t)b * LEN * LEN + (size_t)lt * 256 * LEN + mt * 256;
    __syncthreads();
    #pragma unroll
    for (int h = 0; h < 2; ++h) {
        if (wr == h) {
            #pragma unroll
            for (int n = 0; n < 4; ++n) {
                const int col = wc * 64 + n * 16 + c0;
                const int m_g = mt * 256 + col;
                const int keepcol = mask[b * LEN + m_g];
                #pragma unroll
                for (int m = 0; m < 8; ++m)
                    #pragma unroll
                    for (int i = 0; i < 4; ++i) {
                        const int row = m * 16 + r0 + i;
                        const int l_g = lt * 256 + h * 128 + row;
                        const bool keep = (l_g == m_g) || ((m_g <= l_g) && (keepcol != 0));
                        float v = keep ? acc[m][n][i] * smask[l_g * LEN + m_g] : 0.f;
                        v = fmaxf(v, 0.f);
                        lds[row * EP + col] = (f16)(v * v);
                    }
            }
        }
        __syncthreads();
        copy_half(lds, gbase, 512, h);
        __syncthreads();
    }
}

// ---- batched p@v -> out f32; causal K truncation; long row-panels first ----
// 256 blocks: bid = (b&7) + 8*(inner + 4*(b>>3)); inner = (1-lt)*2 + ht
__global__ __launch_bounds__(512, 2) void k_pv8(const f16* __restrict__ p,
                                                const f16* __restrict__ vt,
                                                float* __restrict__ out)
{
    __shared__ __align__(16) f16 lds[4 * TP];
    const int bid = blockIdx.x;
    const int inner = (bid >> 3) & 3;
    const int b = (bid & 7) + 8 * (bid >> 5);
    const int lt = 1 - (inner >> 1), ht = inner & 1;
    f32x4 acc[8][4];
    gemm8p(p + (size_t)b * LEN * LEN + (size_t)lt * 256 * LEN,
           vt + (size_t)b * HID * LEN + (size_t)ht * 256 * LEN,
           (lt + 1) * 8, lds, acc);
    EPI_IDX();
    // undo q,k 2^10 lifts (squared -> 2^40) and /(L*H)=2^18 : 2^-58 exact
    const float SCALE = 3.4694469519536142e-18f;
    #pragma unroll
    for (int m = 0; m < 8; ++m)
        #pragma unroll
        for (int n = 0; n < 4; ++n) {
            const int h_g = ht * 256 + wc * 64 + n * 16 + c0;
            #pragma unroll
            for (int i = 0; i < 4; ++i) {
                const int l_g = lt * 256 + wr * 128 + m * 16 + r0 + i;
                out[(size_t)b * LEN * HID + (size_t)l_g * HID + h_g] = acc[m][n][i] * SCALE;
            }
        }
}

// ---- one prep launch: gather(x) + 4x weight f2h + smask ----
__global__ __launch_bounds__(256) void k_prep(const int* __restrict__ pos,
                                              const float* __restrict__ item_emb,
                                              const float* __restrict__ pos_emb,
                                              f16* __restrict__ x,
                                              const float* __restrict__ Wz,
                                              const float* __restrict__ Wv,
                                              const float* __restrict__ Wq,
                                              const float* __restrict__ Wk,
                                              f16* __restrict__ Wzh,
                                              f16* __restrict__ Wvh,
                                              f16* __restrict__ Wqh,
                                              f16* __restrict__ Wkh,
                                              const float* __restrict__ sw,
                                              const float* __restrict__ gum,
                                              float* __restrict__ smask)
{
    const int bid = blockIdx.x;
    const int tid = threadIdx.x;
    if (bid < 16384) {                       // gather: x = item_emb[pos] + pos_emb
        const int t = bid * 256 + tid;
        const int i = t >> 7;
        const int c = t & 127;
        const int l = i & (LEN - 1);
        const int item = pos[i];
        const float4 a  = ((const float4*)(item_emb + (size_t)item * HID))[c];
        const float4 b4 = ((const float4*)(pos_emb + (size_t)l * HID))[c];
        f16x4 o = { (f16)(a.x + b4.x), (f16)(a.y + b4.y),
                    (f16)(a.z + b4.z), (f16)(a.w + b4.w) };
        *(f16x4*)(x + (size_t)t * 4) = o;
    } else if (bid < 16384 + 1024) {         // weight f32 -> f16
        const int r = bid - 16384;
        const int w = r >> 8;
        const float* s = (w == 0) ? Wz : (w == 1) ? Wv : (w == 2) ? Wq : Wk;
        f16* d = (w == 0) ? Wzh : (w == 1) ? Wvh : (w == 2) ? Wqh : Wkh;
        const int t = (r & 255) * 256 + tid;
        const float4 v = ((const float4*)s)[t];
        f16x4 o = { (f16)v.x, (f16)v.y, (f16)v.z, (f16)v.w };
        *(f16x4*)(d + (size_t)t * 4) = o;
    } else {                                 // gumbel-sigmoid smask (fp32)
        const int t = (bid - 16384 - 1024) * 256 + tid;
        const float4 w4 = ((const float4*)sw)[t];
        const float4 g4 = ((const float4*)gum)[t];
        float4 o;
        o.x = __builtin_amdgcn_rcpf(1.f + __expf(-(__logf(w4.x / (1.f - w4.x)) + g4.x) * 5.f));
        o.y = __builtin_amdgcn_rcpf(1.f + __expf(-(__logf(w4.y / (1.f - w4.y)) + g4.y) * 5.f));
        o.z = __builtin_amdgcn_rcpf(1.f + __expf(-(__logf(w4.z / (1.f - w4.z)) + g4.z) * 5.f));
        o.w = __builtin_amdgcn_rcpf(1.f + __expf(-(__logf(w4.w / (1.f - w4.w)) + g4.w) * 5.f));
        ((float4*)smask)[t] = o;
    }
}

extern "C" void kernel_launch(void* const* d_in, const int* in_sizes, int n_in,
                              void* d_out, int out_size, void* d_ws, size_t ws_size,
                              hipStream_t stream)
{
    const int*   positives = (const int*)  d_in[0];
    const int*   mask      = (const int*)  d_in[1];
    const float* item_emb  = (const float*)d_in[2];
    const float* pos_emb   = (const float*)d_in[3];
    const float* Wz        = (const float*)d_in[4];
    const float* Wv        = (const float*)d_in[5];
    const float* Wq        = (const float*)d_in[6];
    const float* Wk        = (const float*)d_in[7];
    const float* gamma_q   = (const float*)d_in[8];
    const float* beta_q    = (const float*)d_in[9];
    const float* gamma_k   = (const float*)d_in[10];
    const float* beta_k    = (const float*)d_in[11];
    const float* sparse_w  = (const float*)d_in[12];
    const float* gumbel    = (const float*)d_in[13];
    float* out = (float*)d_out;

    char* ws = (char*)d_ws;
    const size_t BUFB = (size_t)BATCH * LEN * HID * sizeof(f16);  // 32 MB
    f16* buf0 = (f16*)ws;                // x -> p
    f16* buf1 = (f16*)(ws + BUFB);       // z
    f16* buf2 = (f16*)(ws + 2 * BUFB);   // vt
    f16* qh   = (f16*)(ws + 3 * BUFB);   // q
    f16* kh   = (f16*)(ws + 4 * BUFB);   // k
    f16* Wzh  = (f16*)(ws + 5 * BUFB);
    f16* Wvh  = Wzh + LEN * HID;
    f16* Wqh  = Wvh + LEN * HID;
    f16* Wkh  = Wqh + LEN * HID;
    float* smask = (float*)(Wkh + LEN * HID);

    k_prep<<<16384 + 1024 + 256, 256, 0, stream>>>(
        positives, item_emb, pos_emb, buf0,
        Wz, Wv, Wq, Wk, Wzh, Wvh, Wqh, Wkh,
        sparse_w, gumbel, smask);

    k_zv8<<<512, 512, 0, stream>>>(buf0, Wzh, Wvh, buf1, buf2);

    k_qkp8<<<512, 512, 0, stream>>>(buf1, Wqh, Wkh,
                                    gamma_q, beta_q, gamma_k, beta_k, qh, kh);

    k_qk8<<<192, 512, 0, stream>>>(qh, kh, mask, smask, buf0);

    k_pv8<<<256, 512, 0, stream>>>(buf0, buf2, out);
}

// Round 6
// 371.704 us; speedup vs baseline: 1.8100x; 1.0552x over previous
//
#include <hip/hip_runtime.h>
#include <hip/hip_fp16.h>
#include <math.h>

typedef _Float16 f16;
typedef unsigned int u32;
typedef _Float16 f16x8 __attribute__((ext_vector_type(8)));
typedef _Float16 f16x4 __attribute__((ext_vector_type(4)));
typedef float    f32x4 __attribute__((ext_vector_type(4)));

constexpr int LEN  = 512;
constexpr int HID  = 512;
constexpr int BATCH = 64;

// ---- async global->LDS, 16B per lane. lds ptr must be wave-uniform. ----
__device__ __forceinline__ void gload16(const f16* g, f16* l) {
    __builtin_amdgcn_global_load_lds((const __attribute__((address_space(1))) u32*)g,
                                     (__attribute__((address_space(3))) u32*)l,
                                     16, 0, 0);
}

__device__ __forceinline__ float silu_f(float v) {
    return v * __builtin_amdgcn_rcpf(1.f + __expf(-v));
}

// ---- shared staging pass: 128 rows x 32 k-cols from a stride-512 matrix ----
// chunk-XOR swizzle both sides (rule 21): source chunk = (tid&3)^((row>>1)&3);
// matching read slot = ((lane>>4)^((mf>>1)&3)). 16B-position = (row&1)<<2|slot
// -> a 16-row fragment group covers all 8 positions twice = 2-way = free (m136).
__device__ __forceinline__ void stage_pass(const f16* __restrict__ g, f16* l) {
    const int tid = threadIdx.x;
    const int row = tid >> 2;                       // 0..127
    const int sc  = (tid & 3) ^ ((row >> 1) & 3);   // inverse-swizzled chunk
    gload16(g + (size_t)row * 512 + sc * 8, l + (tid >> 6) * 512);
}

// ============================================================================
// CORE A (weight-B kernels): 256x256 8-wave phase core. BK=32, 4 tile-buffers
// (128KB LDS, 1 block/CU), tile-granular 3-ahead prefetch, counted vmcnt.
// Measured (R5): improves k_zv8/k_qkp8 below the 61us fill kernels (vs 70us R1).
// REQUIRES operand reuse across blocks (weight B keeps L2 hot); do NOT use for
// batch-private small-grid kernels (R5: k_qk8 86us @ MfmaUtil 5.5%).
// ============================================================================
#define TP 16384   // f16 per tile buffer (32KB): A 2 passes + B 2 passes
#define EP 264     // epilogue pitch (528B/row, 16B-aligned, bank-rotating)

__device__ __forceinline__ void stage_tile4(const f16* __restrict__ A,
                                            const f16* __restrict__ B,
                                            int t, f16* buf) {
    stage_pass(A + t * 32,             buf);            // A rows   0..127
    stage_pass(A + t * 32 + 128 * 512, buf + 4096);     // A rows 128..255
    stage_pass(B + t * 32,             buf + 8192);     // B rows   0..127
    stage_pass(B + t * 32 + 128 * 512, buf + 12288);    // B rows 128..255
}

// acc[8][4]: wave (wr=wv>>2, wc=wv&3) owns rows wr*128..+127, cols wc*64..+63
__device__ __forceinline__ void gemm8p(const f16* __restrict__ A,
                                       const f16* __restrict__ B,
                                       int nt, f16* lds, f32x4 acc[8][4])
{
    const int lane = threadIdx.x & 63;
    const int wv   = threadIdx.x >> 6;
    const int wr = wv >> 2, wc = wv & 3;
    const int mf = lane & 15;
    const int slot = ((lane >> 4) ^ ((mf >> 1) & 3)) * 8;
    const int abase = wr * 4096 + mf * 32 + slot;
    const int bbase = 8192 + (wc >> 1) * 4096 + ((wc & 1) * 64 + mf) * 32 + slot;

    #pragma unroll
    for (int m = 0; m < 8; ++m)
        #pragma unroll
        for (int n = 0; n < 4; ++n)
            acc[m][n] = (f32x4){0.f, 0.f, 0.f, 0.f};

    stage_tile4(A, B, 0, lds);
    stage_tile4(A, B, 1, lds + TP);
    stage_tile4(A, B, 2, lds + 2 * TP);
    asm volatile("s_waitcnt vmcnt(8)" ::: "memory");   // T0 retired; T1,T2 in flight
    __builtin_amdgcn_s_barrier();

    for (int t = 0; t < nt; ++t) {
        f16* buf  = lds + (t & 3) * TP;
        f16* nbuf = lds + ((t + 3) & 3) * TP;
        const bool st = (t + 3 < nt);
        f16x8 af[4], bf[4];

        // ---- phase A: rows 0..63 of wave tile ----
        #pragma unroll
        for (int m = 0; m < 4; ++m) af[m] = *(const f16x8*)(buf + abase + m * 512);
        #pragma unroll
        for (int n = 0; n < 4; ++n) bf[n] = *(const f16x8*)(buf + bbase + n * 512);
        if (st) {
            stage_pass(A + (t + 3) * 32,             nbuf);
            stage_pass(A + (t + 3) * 32 + 128 * 512, nbuf + 4096);
        }
        __builtin_amdgcn_s_barrier();
        asm volatile("s_waitcnt lgkmcnt(0)" ::: "memory");
        __builtin_amdgcn_sched_barrier(0);
        __builtin_amdgcn_s_setprio(1);
        #pragma unroll
        for (int m = 0; m < 4; ++m)
            #pragma unroll
            for (int n = 0; n < 4; ++n)
                acc[m][n] = __builtin_amdgcn_mfma_f32_16x16x32_f16(af[m], bf[n], acc[m][n], 0, 0, 0);
        __builtin_amdgcn_s_setprio(0);
        __builtin_amdgcn_s_barrier();

        // ---- phase B: rows 64..127 (bf held in regs) ----
        #pragma unroll
        for (int m = 0; m < 4; ++m) af[m] = *(const f16x8*)(buf + abase + (m + 4) * 512);
        if (st) {
            stage_pass(B + (t + 3) * 32,             nbuf + 8192);
            stage_pass(B + (t + 3) * 32 + 128 * 512, nbuf + 12288);
        }
        __builtin_amdgcn_s_barrier();
        asm volatile("s_waitcnt lgkmcnt(0)" ::: "memory");
        __builtin_amdgcn_sched_barrier(0);
        __builtin_amdgcn_s_setprio(1);
        #pragma unroll
        for (int m = 0; m < 4; ++m)
            #pragma unroll
            for (int n = 0; n < 4; ++n)
                acc[m + 4][n] = __builtin_amdgcn_mfma_f32_16x16x32_f16(af[m], bf[n], acc[m + 4][n], 0, 0, 0);
        __builtin_amdgcn_s_setprio(0);
        if (t < nt - 3)       { asm volatile("s_waitcnt vmcnt(8)" ::: "memory"); }
        else if (t == nt - 3) { asm volatile("s_waitcnt vmcnt(4)" ::: "memory"); }
        else if (t == nt - 2) { asm volatile("s_waitcnt vmcnt(0)" ::: "memory"); }
        __builtin_amdgcn_s_barrier();
    }
}

// C/D layout (16x16x32): col = lane&15, row = (lane>>4)*4 + reg   [m89-verified]
#define EPI_IDX8() \
    const int lane = threadIdx.x & 63, wv_ = threadIdx.x >> 6;  \
    const int wr = wv_ >> 2, wc = wv_ & 3;                      \
    const int c0 = lane & 15, r0 = (lane >> 4) * 4;

// coalesced copy of rows h*128..+127 (256 cols) from lds[128][EP]
__device__ __forceinline__ void copy_half256(const f16* lds, f16* __restrict__ gout,
                                             int ldo, int h) {
    const int tid = threadIdx.x;
    #pragma unroll
    for (int ph = 0; ph < 8; ++ph) {
        const int r = ph * 16 + (tid >> 5);
        const int c = (tid & 31) * 8;
        *(f16x8*)(gout + (size_t)(h * 128 + r) * ldo + c) = *(const f16x8*)(lds + r * EP + c);
    }
}

// ---- fused z | v^T, 256^2 tiles. 512 blocks, slab-grouped XCD swizzle ----
// bid = (s&7) + 8*ci + 32*(s>>3); ci 0,1: z col-tile ci; ci 2,3: vt ht=ci-2
__global__ __launch_bounds__(512, 2) void k_zv8(const f16* __restrict__ x,
                                                const f16* __restrict__ Wzh,
                                                const f16* __restrict__ Wvh,
                                                f16* __restrict__ z,
                                                f16* __restrict__ vt)
{
    __shared__ __align__(16) f16 lds[4 * TP];      // 128KB
    const int bid = blockIdx.x;
    const int s  = (bid & 7) + 8 * (bid >> 5);     // x-slab 0..127 (256 rows)
    const int ci = (bid >> 3) & 3;
    const f16* A; const f16* Bm; f16* gout;
    if (ci < 2) {                                  // z[s rows, ci col-tile]
        A = x + (size_t)s * 256 * HID;
        Bm = Wzh + (size_t)ci * 256 * HID;
        gout = z + (size_t)s * 256 * HID + ci * 256;
    } else {                                       // vt[h rows, l cols] = Wv @ x^T
        const int ht = ci - 2;
        A = Wvh + (size_t)ht * 256 * HID;
        Bm = x + (size_t)s * 256 * HID;
        gout = vt + (size_t)(s >> 1) * LEN * HID + (size_t)ht * 256 * LEN + (s & 1) * 256;
    }
    f32x4 acc[8][4];
    gemm8p(A, Bm, 16, lds, acc);
    EPI_IDX8();
    __syncthreads();
    #pragma unroll
    for (int h = 0; h < 2; ++h) {
        if (wr == h) {
            #pragma unroll
            for (int m = 0; m < 8; ++m)
                #pragma unroll
                for (int n = 0; n < 4; ++n)
                    #pragma unroll
                    for (int i = 0; i < 4; ++i)
                        lds[(m * 16 + r0 + i) * EP + wc * 64 + n * 16 + c0] =
                            (f16)silu_f(acc[m][n][i]);
        }
        __syncthreads();
        copy_half256(lds, gout, 512, h);
        __syncthreads();
    }
}

// ---- fused q | k projections over z-slabs ----
__global__ __launch_bounds__(512, 2) void k_qkp8(const f16* __restrict__ z,
                                                 const f16* __restrict__ Wqh,
                                                 const f16* __restrict__ Wkh,
                                                 const float* __restrict__ gq,
                                                 const float* __restrict__ bq,
                                                 const float* __restrict__ gk,
                                                 const float* __restrict__ bk,
                                                 f16* __restrict__ qh,
                                                 f16* __restrict__ kh)
{
    __shared__ __align__(16) f16 lds[4 * TP];
    const int bid = blockIdx.x;
    const int s  = (bid & 7) + 8 * (bid >> 5);
    const int ci = (bid >> 3) & 3;
    const bool isq = ci < 2;
    const int ct = ci & 1;
    const f16* W = isq ? Wqh : Wkh;
    const float* g  = isq ? gq : gk;
    const float* be = isq ? bq : bk;
    f16* outp = isq ? qh : kh;
    f32x4 acc[8][4];
    gemm8p(z + (size_t)s * 256 * HID, W + (size_t)ct * 256 * HID, 16, lds, acc);
    EPI_IDX8();
    f16* gbase = outp + (size_t)s * 256 * HID + ct * 256;
    __syncthreads();
    #pragma unroll
    for (int h = 0; h < 2; ++h) {
        if (wr == h) {
            #pragma unroll
            for (int n = 0; n < 4; ++n) {
                const int col = wc * 64 + n * 16 + c0;
                const int jg = ct * 256 + col;
                const float ga = g[jg], ba = be[jg];
                #pragma unroll
                for (int m = 0; m < 8; ++m)
                    #pragma unroll
                    for (int i = 0; i < 4; ++i)
                        lds[(m * 16 + r0 + i) * EP + col] =
                            (f16)((acc[m][n][i] * ga + ba) * 1024.f);
            }
        }
        __syncthreads();
        copy_half256(lds, gbase, 512, h);
        __syncthreads();
    }
}

// ============================================================================
// CORE B (batch-private kernels): 256x128 8-wave core, BK=32, 3 stage bufs
// (72KB) -> 2 blocks/CU. Measured-best (R3, 344us total) for k_qk8/k_pv8:
// inter-block overlap hides cold-operand stalls the 128KB core exposes.
// ============================================================================
#define TUNIT 12288   // f16 per K-tile buffer: A 256x32 (8192) + B 128x32 (4096)
#define EPIP  136     // epilogue pitch (272B/row, 16B-aligned)

__device__ __forceinline__ void stage_tile3(const f16* __restrict__ A,
                                            const f16* __restrict__ B,
                                            int kt, f16* buf) {
    stage_pass(A + kt * 32,             buf);            // A rows   0..127
    stage_pass(A + kt * 32 + 128 * 512, buf + 4096);     // A rows 128..255
    stage_pass(B + kt * 32,             buf + 8192);     // B rows   0..127
}

// acc[4][4]: wave (wr,wc): rows wr*64..+63, cols wc*64..+63 of the 256x128 tile
__device__ __forceinline__ void gemm8b(const f16* __restrict__ A,
                                       const f16* __restrict__ B,
                                       int ksteps, f16* lds, f32x4 acc[4][4])
{
    const int lane = threadIdx.x & 63;
    const int wv   = threadIdx.x >> 6;
    const int wr = wv >> 1, wc = wv & 1;
    const int mf = lane & 15;
    const int slot = ((lane >> 4) ^ ((mf >> 1) & 3)) * 8;
    const int aoff = (wr * 64 + mf) * 32 + slot;
    const int boff = (wc * 64 + mf) * 32 + slot + 8192;

    #pragma unroll
    for (int m = 0; m < 4; ++m)
        #pragma unroll
        for (int n = 0; n < 4; ++n)
            acc[m][n] = (f32x4){0.f, 0.f, 0.f, 0.f};

    stage_tile3(A, B, 0, lds);
    stage_tile3(A, B, 1, lds + TUNIT);
    asm volatile("s_waitcnt vmcnt(3)" ::: "memory");   // tile0 retired, tile1 in flight
    __builtin_amdgcn_s_barrier();

    int cb = 0;
    for (int kt = 0; kt < ksteps; ++kt) {
        f16* buf = lds + cb * TUNIT;
        f16x8 af[4], bf[4];
        #pragma unroll
        for (int m = 0; m < 4; ++m) af[m] = *(const f16x8*)(buf + aoff + m * 512);
        #pragma unroll
        for (int n = 0; n < 4; ++n) bf[n] = *(const f16x8*)(buf + boff + n * 512);
        if (kt + 2 < ksteps) {
            int nb = cb + 2; if (nb >= 3) nb -= 3;
            stage_tile3(A, B, kt + 2, lds + nb * TUNIT);
        }
        asm volatile("s_waitcnt lgkmcnt(0)" ::: "memory");
        __builtin_amdgcn_sched_barrier(0);
        __builtin_amdgcn_s_setprio(1);
        #pragma unroll
        for (int m = 0; m < 4; ++m)
            #pragma unroll
            for (int n = 0; n < 4; ++n)
                acc[m][n] = __builtin_amdgcn_mfma_f32_16x16x32_f16(af[m], bf[n], acc[m][n], 0, 0, 0);
        __builtin_amdgcn_s_setprio(0);
        if (kt + 3 <= ksteps) {                  // kt <= ksteps-3: tile kt+1 ready
            asm volatile("s_waitcnt vmcnt(3)" ::: "memory");
            __builtin_amdgcn_s_barrier();
        } else if (kt + 2 == ksteps) {           // last prefetched tile
            asm volatile("s_waitcnt vmcnt(0)" ::: "memory");
            __builtin_amdgcn_s_barrier();
        }
        cb = cb + 1; if (cb >= 3) cb = 0;
    }
}

#define EPI_IDXB() \
    const int lane = threadIdx.x & 63, wv_ = threadIdx.x >> 6;  \
    const int wr = wv_ >> 1, wc = wv_ & 1;                      \
    const int c0 = lane & 15, r0 = (lane >> 4) * 4;

// coalesced copy of half-tile h (rows h*128..+127, 128 cols) from lds[128][EPIP]
__device__ __forceinline__ void copy_half128(const f16* lds, f16* __restrict__ gout,
                                             int ldo, int h) {
    const int tid = threadIdx.x;
    #pragma unroll
    for (int ph = 0; ph < 4; ++ph) {
        const int r = ph * 32 + (tid >> 4);
        const int c = (tid & 15) * 8;
        *(f16x8*)(gout + (size_t)(h * 128 + r) * ldo + c) = *(const f16x8*)(lds + r * EPIP + c);
    }
}

// ---- batched q@k^T + mask + smask + relu^2 -> p. 6 tri-tiles (256x128) ----
// 384 blocks: bid = (b&7) + 8*(t + 6*(b>>3))
__constant__ int LT6[6] = {0,0,1,1,1,1};
__constant__ int MT6[6] = {0,1,0,1,2,3};

__global__ __launch_bounds__(512, 4) void k_qk8(const f16* __restrict__ q,
                                                const f16* __restrict__ kmat,
                                                const int* __restrict__ mask,
                                                const float* __restrict__ smask,
                                                f16* __restrict__ p)
{
    __shared__ __align__(16) f16 lds[3 * TUNIT];
    const int bid = blockIdx.x;
    const int t = (bid >> 3) % 6;
    const int b = (bid & 7) + 8 * (bid / 48);
    const int lt = LT6[t], mt = MT6[t];
    const size_t boff = (size_t)b * LEN * HID;
    f32x4 acc[4][4];
    gemm8b(q + boff + (size_t)lt * 256 * HID,
           kmat + boff + (size_t)mt * 128 * HID, HID / 32, lds, acc);
    __syncthreads();
    EPI_IDXB();
    f16* gbase = p + (size_t)b * LEN * LEN + (size_t)lt * 256 * LEN + mt * 128;
    #pragma unroll
    for (int h = 0; h < 2; ++h) {
        if ((wr >> 1) == h) {
            const int rb = (wr & 1) * 64;
            #pragma unroll
            for (int n = 0; n < 4; ++n) {
                const int col = wc * 64 + n * 16 + c0;
                const int m_g = mt * 128 + col;
                const int keepcol = mask[b * LEN + m_g];
                #pragma unroll
                for (int m = 0; m < 4; ++m)
                    #pragma unroll
                    for (int i = 0; i < 4; ++i) {
                        const int row = rb + m * 16 + r0 + i;
                        const int l_g = lt * 256 + h * 128 + row;
                        const bool keep = (l_g == m_g) || ((m_g <= l_g) && (keepcol != 0));
                        float v = keep ? acc[m][n][i] * smask[l_g * LEN + m_g] : 0.f;
                        v = fmaxf(v, 0.f);
                        lds[row * EPIP + col] = (f16)(v * v);
                    }
            }
        }
        __syncthreads();
        copy_half128(lds, gbase, 512, h);
        __syncthreads();
    }
}

// ---- batched p@v -> out f32; causal K truncation; long row-panels first ----
// 512 blocks: bid = (b&7) + 8*(inner + 8*(b>>3)); inner = (1-lt)*4 + ht
__global__ __launch_bounds__(512, 4) void k_pv8(const f16* __restrict__ p,
                                                const f16* __restrict__ vt,
                                                float* __restrict__ out)
{
    __shared__ __align__(16) f16 lds[3 * TUNIT];
    const int bid = blockIdx.x;
    const int inner = (bid >> 3) & 7;
    const int b = (bid & 7) + 8 * (bid >> 6);
    const int lt = 1 - (inner >> 2), ht = inner & 3;
    f32x4 acc[4][4];
    gemm8b(p + (size_t)b * LEN * LEN + (size_t)lt * 256 * LEN,
           vt + (size_t)b * HID * LEN + (size_t)ht * 128 * LEN,
           (lt + 1) * 8, lds, acc);
    EPI_IDXB();
    // undo q,k 2^10 lifts (squared -> 2^40) and /(L*H)=2^18 : 2^-58 exact
    const float SCALE = 3.4694469519536142e-18f;
    #pragma unroll
    for (int m = 0; m < 4; ++m)
        #pragma unroll
        for (int n = 0; n < 4; ++n) {
            const int h_g = ht * 128 + wc * 64 + n * 16 + c0;
            #pragma unroll
            for (int i = 0; i < 4; ++i) {
                const int l_g = lt * 256 + wr * 64 + m * 16 + r0 + i;
                out[(size_t)b * LEN * HID + (size_t)l_g * HID + h_g] = acc[m][n][i] * SCALE;
            }
        }
}

// ---- one prep launch: gather(x) + 4x weight f2h + smask ----
__global__ __launch_bounds__(256) void k_prep(const int* __restrict__ pos,
                                              const float* __restrict__ item_emb,
                                              const float* __restrict__ pos_emb,
                                              f16* __restrict__ x,
                                              const float* __restrict__ Wz,
                                              const float* __restrict__ Wv,
                                              const float* __restrict__ Wq,
                                              const float* __restrict__ Wk,
                                              f16* __restrict__ Wzh,
                                              f16* __restrict__ Wvh,
                                              f16* __restrict__ Wqh,
                                              f16* __restrict__ Wkh,
                                              const float* __restrict__ sw,
                                              const float* __restrict__ gum,
                                              float* __restrict__ smask)
{
    const int bid = blockIdx.x;
    const int tid = threadIdx.x;
    if (bid < 16384) {                       // gather: x = item_emb[pos] + pos_emb
        const int t = bid * 256 + tid;
        const int i = t >> 7;
        const int c = t & 127;
        const int l = i & (LEN - 1);
        const int item = pos[i];
        const float4 a  = ((const float4*)(item_emb + (size_t)item * HID))[c];
        const float4 b4 = ((const float4*)(pos_emb + (size_t)l * HID))[c];
        f16x4 o = { (f16)(a.x + b4.x), (f16)(a.y + b4.y),
                    (f16)(a.z + b4.z), (f16)(a.w + b4.w) };
        *(f16x4*)(x + (size_t)t * 4) = o;
    } else if (bid < 16384 + 1024) {         // weight f32 -> f16
        const int r = bid - 16384;
        const int w = r >> 8;
        const float* s = (w == 0) ? Wz : (w == 1) ? Wv : (w == 2) ? Wq : Wk;
        f16* d = (w == 0) ? Wzh : (w == 1) ? Wvh : (w == 2) ? Wqh : Wkh;
        const int t = (r & 255) * 256 + tid;
        const float4 v = ((const float4*)s)[t];
        f16x4 o = { (f16)v.x, (f16)v.y, (f16)v.z, (f16)v.w };
        *(f16x4*)(d + (size_t)t * 4) = o;
    } else {                                 // gumbel-sigmoid smask (fp32)
        const int t = (bid - 16384 - 1024) * 256 + tid;
        const float4 w4 = ((const float4*)sw)[t];
        const float4 g4 = ((const float4*)gum)[t];
        float4 o;
        o.x = __builtin_amdgcn_rcpf(1.f + __expf(-(__logf(w4.x / (1.f - w4.x)) + g4.x) * 5.f));
        o.y = __builtin_amdgcn_rcpf(1.f + __expf(-(__logf(w4.y / (1.f - w4.y)) + g4.y) * 5.f));
        o.z = __builtin_amdgcn_rcpf(1.f + __expf(-(__logf(w4.z / (1.f - w4.z)) + g4.z) * 5.f));
        o.w = __builtin_amdgcn_rcpf(1.f + __expf(-(__logf(w4.w / (1.f - w4.w)) + g4.w) * 5.f));
        ((float4*)smask)[t] = o;
    }
}

extern "C" void kernel_launch(void* const* d_in, const int* in_sizes, int n_in,
                              void* d_out, int out_size, void* d_ws, size_t ws_size,
                              hipStream_t stream)
{
    const int*   positives = (const int*)  d_in[0];
    const int*   mask      = (const int*)  d_in[1];
    const float* item_emb  = (const float*)d_in[2];
    const float* pos_emb   = (const float*)d_in[3];
    const float* Wz        = (const float*)d_in[4];
    const float* Wv        = (const float*)d_in[5];
    const float* Wq        = (const float*)d_in[6];
    const float* Wk        = (const float*)d_in[7];
    const float* gamma_q   = (const float*)d_in[8];
    const float* beta_q    = (const float*)d_in[9];
    const float* gamma_k   = (const float*)d_in[10];
    const float* beta_k    = (const float*)d_in[11];
    const float* sparse_w  = (const float*)d_in[12];
    const float* gumbel    = (const float*)d_in[13];
    float* out = (float*)d_out;

    char* ws = (char*)d_ws;
    const size_t BUFB = (size_t)BATCH * LEN * HID * sizeof(f16);  // 32 MB
    f16* buf0 = (f16*)ws;                // x -> p
    f16* buf1 = (f16*)(ws + BUFB);       // z
    f16* buf2 = (f16*)(ws + 2 * BUFB);   // vt
    f16* qh   = (f16*)(ws + 3 * BUFB);   // q
    f16* kh   = (f16*)(ws + 4 * BUFB);   // k
    f16* Wzh  = (f16*)(ws + 5 * BUFB);
    f16* Wvh  = Wzh + LEN * HID;
    f16* Wqh  = Wvh + LEN * HID;
    f16* Wkh  = Wqh + LEN * HID;
    float* smask = (float*)(Wkh + LEN * HID);

    k_prep<<<16384 + 1024 + 256, 256, 0, stream>>>(
        positives, item_emb, pos_emb, buf0,
        Wz, Wv, Wq, Wk, Wzh, Wvh, Wqh, Wkh,
        sparse_w, gumbel, smask);

    k_zv8<<<512, 512, 0, stream>>>(buf0, Wzh, Wvh, buf1, buf2);

    k_qkp8<<<512, 512, 0, stream>>>(buf1, Wqh, Wkh,
                                    gamma_q, beta_q, gamma_k, beta_k, qh, kh);

    k_qk8<<<384, 512, 0, stream>>>(qh, kh, mask, smask, buf0);

    k_pv8<<<512, 512, 0, stream>>>(buf0, buf2, out);
}

// Round 7
// 353.677 us; speedup vs baseline: 1.9023x; 1.0510x over previous
//
#include <hip/hip_runtime.h>
#include <hip/hip_fp16.h>
#include <math.h>

typedef _Float16 f16;
typedef unsigned int u32;
typedef _Float16 f16x8 __attribute__((ext_vector_type(8)));
typedef _Float16 f16x4 __attribute__((ext_vector_type(4)));
typedef float    f32x4 __attribute__((ext_vector_type(4)));

constexpr int LEN  = 512;
constexpr int HID  = 512;
constexpr int BATCH = 64;

// ---- async global->LDS, 16B per lane. lds ptr must be wave-uniform. ----
__device__ __forceinline__ void gload16(const f16* g, f16* l) {
    __builtin_amdgcn_global_load_lds((const __attribute__((address_space(1))) u32*)g,
                                     (__attribute__((address_space(3))) u32*)l,
                                     16, 0, 0);
}

__device__ __forceinline__ float silu_f(float v) {
    return v * __builtin_amdgcn_rcpf(1.f + __expf(-v));
}

// ============================================================================
// 256x128 8-wave core, BK=32, 3 stage bufs (72KB) -> 2 blocks/CU.
// Verified-best structure for this problem's short K-loops (R3: 344us; beats
// 256^2 1-block/CU deep pipe in all 4 kernels, R5/R6 A/B). 2-ahead counted
// vmcnt; ONE barrier per iter (3-buffer reuse distance makes it race-free).
// LDS chunk swizzle both sides (rule 21): source chunk = (tid&3)^((row>>1)&3),
// read slot = ((lane>>4)^((mf>>1)&3)); 16B-position = (row&1)<<2|slot ->
// 16-row fragment group covers all 8 positions twice -> 2-way = free (m136).
// ============================================================================
#define TUNIT 12288   // f16 per K-tile buffer: A 256x32 (8192) + B 128x32 (4096)
#define EPIP  136     // epilogue pitch (272B/row, 16B-aligned)

__device__ __forceinline__ void stage_pass(const f16* __restrict__ g, f16* l) {
    const int tid = threadIdx.x;
    const int row = tid >> 2;                       // 0..127
    const int sc  = (tid & 3) ^ ((row >> 1) & 3);   // inverse-swizzled chunk
    gload16(g + (size_t)row * 512 + sc * 8, l + (tid >> 6) * 512);
}

__device__ __forceinline__ void stage_tile(const f16* __restrict__ A,
                                           const f16* __restrict__ B,
                                           int kt, f16* buf) {
    stage_pass(A + kt * 32,             buf);            // A rows   0..127
    stage_pass(A + kt * 32 + 128 * 512, buf + 4096);     // A rows 128..255
    stage_pass(B + kt * 32,             buf + 8192);     // B rows   0..127
}

// acc[4][4]: wave (wr,wc): rows wr*64..+63, cols wc*64..+63 of the 256x128 tile
__device__ __forceinline__ void gemm8b(const f16* __restrict__ A,
                                       const f16* __restrict__ B,
                                       int ksteps, f16* lds, f32x4 acc[4][4])
{
    const int lane = threadIdx.x & 63;
    const int wv   = threadIdx.x >> 6;
    const int wr = wv >> 1, wc = wv & 1;
    const int mf = lane & 15;
    const int slot = ((lane >> 4) ^ ((mf >> 1) & 3)) * 8;
    const int aoff = (wr * 64 + mf) * 32 + slot;
    const int boff = (wc * 64 + mf) * 32 + slot + 8192;

    #pragma unroll
    for (int m = 0; m < 4; ++m)
        #pragma unroll
        for (int n = 0; n < 4; ++n)
            acc[m][n] = (f32x4){0.f, 0.f, 0.f, 0.f};

    stage_tile(A, B, 0, lds);
    stage_tile(A, B, 1, lds + TUNIT);
    asm volatile("s_waitcnt vmcnt(3)" ::: "memory");   // tile0 retired, tile1 in flight
    __builtin_amdgcn_s_barrier();

    int cb = 0;
    for (int kt = 0; kt < ksteps; ++kt) {
        f16* buf = lds + cb * TUNIT;
        f16x8 af[4], bf[4];
        #pragma unroll
        for (int m = 0; m < 4; ++m) af[m] = *(const f16x8*)(buf + aoff + m * 512);
        #pragma unroll
        for (int n = 0; n < 4; ++n) bf[n] = *(const f16x8*)(buf + boff + n * 512);
        if (kt + 2 < ksteps) {
            int nb = cb + 2; if (nb >= 3) nb -= 3;
            stage_tile(A, B, kt + 2, lds + nb * TUNIT);
        }
        asm volatile("s_waitcnt lgkmcnt(0)" ::: "memory");
        __builtin_amdgcn_sched_barrier(0);
        __builtin_amdgcn_s_setprio(1);
        #pragma unroll
        for (int m = 0; m < 4; ++m)
            #pragma unroll
            for (int n = 0; n < 4; ++n)
                acc[m][n] = __builtin_amdgcn_mfma_f32_16x16x32_f16(af[m], bf[n], acc[m][n], 0, 0, 0);
        __builtin_amdgcn_s_setprio(0);
        if (kt + 3 <= ksteps) {                  // kt <= ksteps-3: tile kt+1 ready
            asm volatile("s_waitcnt vmcnt(3)" ::: "memory");
            __builtin_amdgcn_s_barrier();
        } else if (kt + 2 == ksteps) {           // last prefetched tile
            asm volatile("s_waitcnt vmcnt(0)" ::: "memory");
            __builtin_amdgcn_s_barrier();
        }
        cb = cb + 1; if (cb >= 3) cb = 0;
    }
}

// C/D layout (16x16x32): col = lane&15, row = (lane>>4)*4 + reg   [m89-verified]
#define EPI_IDX() \
    const int lane = threadIdx.x & 63, wv_ = threadIdx.x >> 6;  \
    const int wr = wv_ >> 1, wc = wv_ & 1;                      \
    const int c0 = lane & 15, r0 = (lane >> 4) * 4;

// coalesced copy of half-tile h (rows h*128..+127) from lds[128][EPIP]
__device__ __forceinline__ void copy_half(const f16* lds, f16* __restrict__ gout,
                                          int ldo, int h) {
    const int tid = threadIdx.x;
    #pragma unroll
    for (int ph = 0; ph < 4; ++ph) {
        const int r = ph * 32 + (tid >> 4);
        const int c = (tid & 15) * 8;
        *(f16x8*)(gout + (size_t)(h * 128 + r) * ldo + c) = *(const f16x8*)(lds + r * EPIP + c);
    }
}

// ---- fused z | v^T. 1024 blocks: slab s's 8 consumers share bid%8 (XCD) ----
// bid = (s&7) + 8*ci + 64*(s>>3); ci 0-3: z nt=ci; ci 4-7: vt (ht,lh)
__global__ __launch_bounds__(512, 4) void k_zv8(const f16* __restrict__ x,
                                                const f16* __restrict__ Wzh,
                                                const f16* __restrict__ Wvh,
                                                f16* __restrict__ z,
                                                f16* __restrict__ vt)
{
    __shared__ __align__(16) f16 lds[3 * TUNIT];   // 72KB
    const int bid = blockIdx.x;
    const int s  = (bid & 7) + 8 * (bid >> 6);     // x-slab 0..127 (256 rows)
    const int ci = (bid >> 3) & 7;
    const f16* A; const f16* Bm; f16* gout;
    if (ci < 4) {                                  // z[s rows, nt=ci cols]
        A = x + (size_t)s * 256 * HID;
        Bm = Wzh + (size_t)ci * 128 * HID;
        gout = z + (size_t)s * 256 * HID + ci * 128;
    } else {                                       // vt[h rows, l cols] = Wv @ x^T
        const int ht = (ci - 4) >> 1, lh = (ci - 4) & 1;
        A = Wvh + (size_t)ht * 256 * HID;
        Bm = x + ((size_t)s * 256 + lh * 128) * HID;
        gout = vt + (size_t)(s >> 1) * LEN * HID + (size_t)ht * 256 * LEN
                  + (s & 1) * 256 + lh * 128;
    }
    f32x4 acc[4][4];
    gemm8b(A, Bm, HID / 32, lds, acc);
    __syncthreads();
    EPI_IDX();
    #pragma unroll
    for (int h = 0; h < 2; ++h) {
        if ((wr >> 1) == h) {
            const int rb = (wr & 1) * 64;
            #pragma unroll
            for (int m = 0; m < 4; ++m)
                #pragma unroll
                for (int n = 0; n < 4; ++n)
                    #pragma unroll
                    for (int i = 0; i < 4; ++i)
                        lds[(rb + m * 16 + r0 + i) * EPIP + wc * 64 + n * 16 + c0] =
                            (f16)silu_f(acc[m][n][i]);
        }
        __syncthreads();
        copy_half(lds, gout, 512, h);
        __syncthreads();
    }
}

// ---- fused q | k projections, same structure over z-slabs ----
__global__ __launch_bounds__(512, 4) void k_qkp8(const f16* __restrict__ z,
                                                 const f16* __restrict__ Wqh,
                                                 const f16* __restrict__ Wkh,
                                                 const float* __restrict__ gq,
                                                 const float* __restrict__ bq,
                                                 const float* __restrict__ gk,
                                                 const float* __restrict__ bk,
                                                 f16* __restrict__ qh,
                                                 f16* __restrict__ kh)
{
    __shared__ __align__(16) f16 lds[3 * TUNIT];
    const int bid = blockIdx.x;
    const int s  = (bid & 7) + 8 * (bid >> 6);
    const int ci = (bid >> 3) & 7;
    const bool isq = ci < 4;
    const int nt = ci & 3;
    const f16* W = isq ? Wqh : Wkh;
    const float* g  = isq ? gq : gk;
    const float* be = isq ? bq : bk;
    f16* outp = isq ? qh : kh;
    f32x4 acc[4][4];
    gemm8b(z + (size_t)s * 256 * HID, W + (size_t)nt * 128 * HID, HID / 32, lds, acc);
    __syncthreads();
    EPI_IDX();
    f16* gbase = outp + (size_t)s * 256 * HID + nt * 128;
    #pragma unroll
    for (int h = 0; h < 2; ++h) {
        if ((wr >> 1) == h) {
            const int rb = (wr & 1) * 64;
            #pragma unroll
            for (int n = 0; n < 4; ++n) {
                const int col = wc * 64 + n * 16 + c0;
                const int jg = nt * 128 + col;
                const float ga = g[jg], ba = be[jg];
                #pragma unroll
                for (int m = 0; m < 4; ++m)
                    #pragma unroll
                    for (int i = 0; i < 4; ++i)
                        lds[(rb + m * 16 + r0 + i) * EPIP + col] =
                            (f16)((acc[m][n][i] * ga + ba) * 1024.f);
            }
        }
        __syncthreads();
        copy_half(lds, gbase, 512, h);
        __syncthreads();
    }
}

// ---- batched q@k^T + mask + smask + relu^2 -> p. 6 tri-tiles (256x128) ----
// 384 blocks: bid = (b&7) + 8*(t + 6*(b>>3))
__constant__ int LT6[6] = {0,0,1,1,1,1};
__constant__ int MT6[6] = {0,1,0,1,2,3};

__global__ __launch_bounds__(512, 4) void k_qk8(const f16* __restrict__ q,
                                                const f16* __restrict__ kmat,
                                                const int* __restrict__ mask,
                                                const float* __restrict__ smask,
                                                f16* __restrict__ p)
{
    __shared__ __align__(16) f16 lds[3 * TUNIT];
    const int bid = blockIdx.x;
    const int t = (bid >> 3) % 6;
    const int b = (bid & 7) + 8 * (bid / 48);
    const int lt = LT6[t], mt = MT6[t];
    const size_t boff = (size_t)b * LEN * HID;
    f32x4 acc[4][4];
    gemm8b(q + boff + (size_t)lt * 256 * HID,
           kmat + boff + (size_t)mt * 128 * HID, HID / 32, lds, acc);
    __syncthreads();
    EPI_IDX();
    f16* gbase = p + (size_t)b * LEN * LEN + (size_t)lt * 256 * LEN + mt * 128;
    #pragma unroll
    for (int h = 0; h < 2; ++h) {
        if ((wr >> 1) == h) {
            const int rb = (wr & 1) * 64;
            #pragma unroll
            for (int n = 0; n < 4; ++n) {
                const int col = wc * 64 + n * 16 + c0;
                const int m_g = mt * 128 + col;
                const int keepcol = mask[b * LEN + m_g];
                #pragma unroll
                for (int m = 0; m < 4; ++m)
                    #pragma unroll
                    for (int i = 0; i < 4; ++i) {
                        const int row = rb + m * 16 + r0 + i;
                        const int l_g = lt * 256 + h * 128 + row;
                        const bool keep = (l_g == m_g) || ((m_g <= l_g) && (keepcol != 0));
                        float v = keep ? acc[m][n][i] * smask[l_g * LEN + m_g] : 0.f;
                        v = fmaxf(v, 0.f);
                        lds[row * EPIP + col] = (f16)(v * v);
                    }
            }
        }
        __syncthreads();
        copy_half(lds, gbase, 512, h);
        __syncthreads();
    }
}

// ---- batched p@v -> out f32; causal K truncation; long row-panels first ----
// 512 blocks: bid = (b&7) + 8*(inner + 8*(b>>3)); inner = (1-lt)*4 + ht
__global__ __launch_bounds__(512, 4) void k_pv8(const f16* __restrict__ p,
                                                const f16* __restrict__ vt,
                                                float* __restrict__ out)
{
    __shared__ __align__(16) f16 lds[3 * TUNIT];
    const int bid = blockIdx.x;
    const int inner = (bid >> 3) & 7;
    const int b = (bid & 7) + 8 * (bid >> 6);
    const int lt = 1 - (inner >> 2), ht = inner & 3;
    f32x4 acc[4][4];
    gemm8b(p + (size_t)b * LEN * LEN + (size_t)lt * 256 * LEN,
           vt + (size_t)b * HID * LEN + (size_t)ht * 128 * LEN,
           (lt + 1) * 8, lds, acc);
    EPI_IDX();
    // undo q,k 2^10 lifts (squared -> 2^40) and /(L*H)=2^18 : 2^-58 exact
    const float SCALE = 3.4694469519536142e-18f;
    #pragma unroll
    for (int m = 0; m < 4; ++m)
        #pragma unroll
        for (int n = 0; n < 4; ++n) {
            const int h_g = ht * 128 + wc * 64 + n * 16 + c0;
            #pragma unroll
            for (int i = 0; i < 4; ++i) {
                const int l_g = lt * 256 + wr * 64 + m * 16 + r0 + i;
                out[(size_t)b * LEN * HID + (size_t)l_g * HID + h_g] = acc[m][n][i] * SCALE;
            }
        }
}

// ---- prep: gather(x) + 4x weight f2h + smask. Grid-stride, 2048 blocks ----
// (R7 change: was 17664 tiny blocks -- G11 anti-pattern; each thread now owns
// 4 chunks of ONE gather row: pos[i] loaded once, 256B-contiguous per 16 lanes)
__global__ __launch_bounds__(256) void k_prep(const int* __restrict__ pos,
                                              const float* __restrict__ item_emb,
                                              const float* __restrict__ pos_emb,
                                              f16* __restrict__ x,
                                              const float* __restrict__ Wz,
                                              const float* __restrict__ Wv,
                                              const float* __restrict__ Wq,
                                              const float* __restrict__ Wk,
                                              f16* __restrict__ Wzh,
                                              f16* __restrict__ Wvh,
                                              f16* __restrict__ Wqh,
                                              f16* __restrict__ Wkh,
                                              const float* __restrict__ sw,
                                              const float* __restrict__ gum,
                                              float* __restrict__ smask)
{
    const int t0 = blockIdx.x * 256 + threadIdx.x;     // 0..524287

    // ---- gather: 32768 rows x 64 f16x8-chunks; thread owns row t0>>4 ----
    {
        const int i = t0 >> 4;                         // row 0..32767
        const int l = i & (LEN - 1);
        const int item = pos[i];
        const float* ib = item_emb + (size_t)item * HID;
        const float* pb = pos_emb + (size_t)l * HID;
        f16* xb = x + (size_t)i * HID;
        #pragma unroll
        for (int it = 0; it < 4; ++it) {
            const int c = (t0 & 15) + it * 16;         // chunk 0..63
            const float4 a0 = ((const float4*)(ib + c * 8))[0];
            const float4 a1 = ((const float4*)(ib + c * 8 + 4))[0];
            const float4 b0 = ((const float4*)(pb + c * 8))[0];
            const float4 b1 = ((const float4*)(pb + c * 8 + 4))[0];
            f16x8 o = { (f16)(a0.x + b0.x), (f16)(a0.y + b0.y),
                        (f16)(a0.z + b0.z), (f16)(a0.w + b0.w),
                        (f16)(a1.x + b1.x), (f16)(a1.y + b1.y),
                        (f16)(a1.z + b1.z), (f16)(a1.w + b1.w) };
            *(f16x8*)(xb + c * 8) = o;
        }
    }

    // ---- weights f32 -> f16: 4 x 65536 float4 units ----
    if (t0 < 262144) {
        const int w = t0 >> 16;
        const int u = t0 & 65535;
        const float* s = (w == 0) ? Wz : (w == 1) ? Wv : (w == 2) ? Wq : Wk;
        f16* d = (w == 0) ? Wzh : (w == 1) ? Wvh : (w == 2) ? Wqh : Wkh;
        const float4 v = ((const float4*)s)[u];
        f16x4 o = { (f16)v.x, (f16)v.y, (f16)v.z, (f16)v.w };
        *(f16x4*)(d + (size_t)u * 4) = o;
    }

    // ---- gumbel-sigmoid smask (fp32): 65536 float4 units ----
    if (t0 < 65536) {
        const float4 w4 = ((const float4*)sw)[t0];
        const float4 g4 = ((const float4*)gum)[t0];
        float4 o;
        o.x = __builtin_amdgcn_rcpf(1.f + __expf(-(__logf(w4.x / (1.f - w4.x)) + g4.x) * 5.f));
        o.y = __builtin_amdgcn_rcpf(1.f + __expf(-(__logf(w4.y / (1.f - w4.y)) + g4.y) * 5.f));
        o.z = __builtin_amdgcn_rcpf(1.f + __expf(-(__logf(w4.z / (1.f - w4.z)) + g4.z) * 5.f));
        o.w = __builtin_amdgcn_rcpf(1.f + __expf(-(__logf(w4.w / (1.f - w4.w)) + g4.w) * 5.f));
        ((float4*)smask)[t0] = o;
    }
}

extern "C" void kernel_launch(void* const* d_in, const int* in_sizes, int n_in,
                              void* d_out, int out_size, void* d_ws, size_t ws_size,
                              hipStream_t stream)
{
    const int*   positives = (const int*)  d_in[0];
    const int*   mask      = (const int*)  d_in[1];
    const float* item_emb  = (const float*)d_in[2];
    const float* pos_emb   = (const float*)d_in[3];
    const float* Wz        = (const float*)d_in[4];
    const float* Wv        = (const float*)d_in[5];
    const float* Wq        = (const float*)d_in[6];
    const float* Wk        = (const float*)d_in[7];
    const float* gamma_q   = (const float*)d_in[8];
    const float* beta_q    = (const float*)d_in[9];
    const float* gamma_k   = (const float*)d_in[10];
    const float* beta_k    = (const float*)d_in[11];
    const float* sparse_w  = (const float*)d_in[12];
    const float* gumbel    = (const float*)d_in[13];
    float* out = (float*)d_out;

    char* ws = (char*)d_ws;
    const size_t BUFB = (size_t)BATCH * LEN * HID * sizeof(f16);  // 32 MB
    f16* buf0 = (f16*)ws;                // x -> p
    f16* buf1 = (f16*)(ws + BUFB);       // z
    f16* buf2 = (f16*)(ws + 2 * BUFB);   // vt
    f16* qh   = (f16*)(ws + 3 * BUFB);   // q
    f16* kh   = (f16*)(ws + 4 * BUFB);   // k
    f16* Wzh  = (f16*)(ws + 5 * BUFB);
    f16* Wvh  = Wzh + LEN * HID;
    f16* Wqh  = Wvh + LEN * HID;
    f16* Wkh  = Wqh + LEN * HID;
    float* smask = (float*)(Wkh + LEN * HID);

    k_prep<<<2048, 256, 0, stream>>>(
        positives, item_emb, pos_emb, buf0,
        Wz, Wv, Wq, Wk, Wzh, Wvh, Wqh, Wkh,
        sparse_w, gumbel, smask);

    k_zv8<<<1024, 512, 0, stream>>>(buf0, Wzh, Wvh, buf1, buf2);

    k_qkp8<<<1024, 512, 0, stream>>>(buf1, Wqh, Wkh,
                                     gamma_q, beta_q, gamma_k, beta_k, qh, kh);

    k_qk8<<<384, 512, 0, stream>>>(qh, kh, mask, smask, buf0);

    k_pv8<<<512, 512, 0, stream>>>(buf0, buf2, out);
}